// Round 4
// baseline (148.407 us; speedup 1.0000x reference)
//
#include <hip/hip_runtime.h>
#include <hip/hip_fp16.h>

typedef _Float16 f16x8 __attribute__((ext_vector_type(8)));
typedef float    f32x4 __attribute__((ext_vector_type(4)));

#define IMG   512
#define NIMG  64
#define TS_R  32
#define TS_C  64
#define NBLK  (NIMG * (IMG/TS_R) * (IMG/TS_C))   // 8192

#define XST   88     // X/Y plane row stride in halves (16B-mult, bank-spread)
#define XROWS 48
#define HST   56     // H_T row stride in halves (16B-mult, bank-spread)

#define C1F   1.0e-4f
#define C2F   9.0e-4f

// Gaussian tap w(d) for d in [0,10], else 0 (window truncation), normalized by inv.
__device__ __forceinline__ float gw(int d, float inv) {
    float t = (float)(d - 5);
    float v = __expf(-t * t * (1.0f / 4.5f)) * inv;
    return ((unsigned)d <= 10u) ? v : 0.0f;
}

__global__ __launch_bounds__(256, 3)
void ssim_main(const float* __restrict__ x, const float* __restrict__ y,
               float* __restrict__ partial) {
    __shared__ __align__(16) __half Xp[XROWS * XST];      //  8448 B
    __shared__ __align__(16) __half Yp[XROWS * XST];      //  8448 B
    __shared__ __align__(16) __half Ht[5][64 * HST];      // 35840 B (H transposed, per field)
    __shared__ float red[4];

    const int tid  = threadIdx.x;
    const int lane = tid & 63;
    const int wv   = tid >> 6;       // wave 0..3
    const int n0   = wv * 16;        // this wave's N strip (output cols)
    const int g16  = lane >> 4;      // quarter-group 0..3
    const int l16  = lane & 15;

    // Normalizer: sum of the 11 taps.
    float wsum = 0.0f;
    #pragma unroll
    for (int k = 0; k < 11; ++k) {
        float d = (float)(k - 5);
        wsum += __expf(-d * d * (1.0f / 4.5f));
    }
    const float inv = 1.0f / wsum;

    const int img = blockIdx.z;
    const int r0  = blockIdx.y * TS_R;
    const int c0  = blockIdx.x * TS_C;
    const float* xb = x + (size_t)img * IMG * IMG;
    const float* yb = y + (size_t)img * IMG * IMG;

    // ---- Stage X,Y tiles as fp16 planes (rows 0..41 real, cols 0..73 real, rest 0) ----
    for (int idx = tid; idx < XROWS * (XST / 2); idx += 256) {   // 48*44 = 2112
        int i    = idx / (XST / 2);
        int jp   = idx - i * (XST / 2);
        int col0 = jp * 2;
        int gr   = r0 - 5 + i;
        int gc   = c0 - 5 + col0;
        bool rok  = (i < 42) & ((unsigned)gr < IMG);
        bool c0ok = rok & (col0 < 74)     & ((unsigned)gc < IMG);
        bool c1ok = rok & (col0 + 1 < 74) & ((unsigned)(gc + 1) < IMG);
        size_t o = (size_t)gr * IMG + gc;
        float xv0 = c0ok ? xb[o]     : 0.0f;
        float xv1 = c1ok ? xb[o + 1] : 0.0f;
        float yv0 = c0ok ? yb[o]     : 0.0f;
        float yv1 = c1ok ? yb[o + 1] : 0.0f;
        *(__half2*)&Xp[i * XST + col0] = __floats2half2_rn(xv0, xv1);
        *(__half2*)&Yp[i * XST + col0] = __floats2half2_rn(yv0, yv1);
    }
    __syncthreads();

    // ---- Banded Gaussian B-frags for H pass: B[k][n] = w(k - n), K=96, N strip=16 ----
    f16x8 WhB[3];
    #pragma unroll
    for (int ks = 0; ks < 3; ++ks) {
        int kb = ks * 32 + g16 * 8;
        int n  = n0 + l16;
        #pragma unroll
        for (int j = 0; j < 8; ++j)
            WhB[ks][j] = (_Float16)gw(kb + j - n, inv);
    }
    // ---- Banded Gaussian A-frags for V pass: A[r][k] = w(k - r), M=32, K=64 ----
    f16x8 WvA[2][2];
    #pragma unroll
    for (int mt = 0; mt < 2; ++mt)
        #pragma unroll
        for (int ks = 0; ks < 2; ++ks) {
            int kb = ks * 32 + g16 * 8;
            int r  = mt * 16 + l16;
            #pragma unroll
            for (int j = 0; j < 8; ++j)
                WvA[mt][ks][j] = (_Float16)gw(kb + j - r, inv);
        }

    // ---- H pass: H(48x16 strip) = X(48x88) * WhB, 5 fields, fp32 accum ----
    #pragma unroll
    for (int mt = 0; mt < 3; ++mt) {
        f32x4 aX  = {0.f,0.f,0.f,0.f}, aY  = {0.f,0.f,0.f,0.f};
        f32x4 aXX = {0.f,0.f,0.f,0.f}, aYY = {0.f,0.f,0.f,0.f};
        f32x4 aXY = {0.f,0.f,0.f,0.f};
        #pragma unroll
        for (int ks = 0; ks < 3; ++ks) {
            f16x8 xf, yf;
            if (ks < 2 || g16 < 2) {
                int off = (mt * 16 + l16) * XST + ks * 32 + g16 * 8;
                xf = *(const f16x8*)&Xp[off];
                yf = *(const f16x8*)&Yp[off];
            } else {
                #pragma unroll
                for (int j = 0; j < 8; ++j) { xf[j] = (_Float16)0.f; yf[j] = (_Float16)0.f; }
            }
            f16x8 xx = xf * xf;
            f16x8 yy = yf * yf;
            f16x8 xy = xf * yf;
            aX  = __builtin_amdgcn_mfma_f32_16x16x32_f16(xf, WhB[ks], aX,  0, 0, 0);
            aY  = __builtin_amdgcn_mfma_f32_16x16x32_f16(yf, WhB[ks], aY,  0, 0, 0);
            aXX = __builtin_amdgcn_mfma_f32_16x16x32_f16(xx, WhB[ks], aXX, 0, 0, 0);
            aYY = __builtin_amdgcn_mfma_f32_16x16x32_f16(yy, WhB[ks], aYY, 0, 0, 0);
            aXY = __builtin_amdgcn_mfma_f32_16x16x32_f16(xy, WhB[ks], aXY, 0, 0, 0);
        }
        // Write back to H_T (fp16): row n, cols m = mt*16 + g16*4 + reg
        int ho = (n0 + l16) * HST + mt * 16 + g16 * 4;
        {
            uint2 v;
            __half2 p0, p1;
            p0 = __floats2half2_rn(aX[0], aX[1]);  p1 = __floats2half2_rn(aX[2], aX[3]);
            v.x = *(uint*)&p0; v.y = *(uint*)&p1;  *(uint2*)&Ht[0][ho] = v;
            p0 = __floats2half2_rn(aY[0], aY[1]);  p1 = __floats2half2_rn(aY[2], aY[3]);
            v.x = *(uint*)&p0; v.y = *(uint*)&p1;  *(uint2*)&Ht[1][ho] = v;
            p0 = __floats2half2_rn(aXX[0], aXX[1]); p1 = __floats2half2_rn(aXX[2], aXX[3]);
            v.x = *(uint*)&p0; v.y = *(uint*)&p1;  *(uint2*)&Ht[2][ho] = v;
            p0 = __floats2half2_rn(aYY[0], aYY[1]); p1 = __floats2half2_rn(aYY[2], aYY[3]);
            v.x = *(uint*)&p0; v.y = *(uint*)&p1;  *(uint2*)&Ht[3][ho] = v;
            p0 = __floats2half2_rn(aXY[0], aXY[1]); p1 = __floats2half2_rn(aXY[2], aXY[3]);
            v.x = *(uint*)&p0; v.y = *(uint*)&p1;  *(uint2*)&Ht[4][ho] = v;
        }
    }
    // No barrier needed: each wave reads only its own H_T strip.

    // ---- V pass: Out(32x16 strip) = WvA(32x64) * H(64x16 strip), 5 fields ----
    f32x4 c0f[5], c1f[5];
    #pragma unroll
    for (int f = 0; f < 5; ++f) {
        c0f[f] = (f32x4){0.f,0.f,0.f,0.f};
        c1f[f] = (f32x4){0.f,0.f,0.f,0.f};
    }
    #pragma unroll
    for (int ks = 0; ks < 2; ++ks) {
        f16x8 bf[5];
        #pragma unroll
        for (int f = 0; f < 5; ++f) {
            if (ks == 0 || g16 < 2) {
                int off = (n0 + l16) * HST + ks * 32 + g16 * 8;
                bf[f] = *(const f16x8*)&Ht[f][off];
            } else {
                #pragma unroll
                for (int j = 0; j < 8; ++j) bf[f][j] = (_Float16)0.f;
            }
        }
        #pragma unroll
        for (int f = 0; f < 5; ++f) {
            c0f[f] = __builtin_amdgcn_mfma_f32_16x16x32_f16(WvA[0][ks], bf[f], c0f[f], 0, 0, 0);
            c1f[f] = __builtin_amdgcn_mfma_f32_16x16x32_f16(WvA[1][ks], bf[f], c1f[f], 0, 0, 0);
        }
    }

    // ---- SSIM epilogue: all 5 fields share C layout; 8 px per lane ----
    float ssum = 0.0f;
    #pragma unroll
    for (int mt = 0; mt < 2; ++mt) {
        #pragma unroll
        for (int r = 0; r < 4; ++r) {
            float mx  = (mt == 0) ? c0f[0][r] : c1f[0][r];
            float my  = (mt == 0) ? c0f[1][r] : c1f[1][r];
            float exx = (mt == 0) ? c0f[2][r] : c1f[2][r];
            float eyy = (mt == 0) ? c0f[3][r] : c1f[3][r];
            float exy = (mt == 0) ? c0f[4][r] : c1f[4][r];
            float mxx = mx * mx, myy = my * my, mxy = mx * my;
            float vx  = exx - mxx;
            float vy  = eyy - myy;
            float vxy = exy - mxy;
            float num = (2.0f * mxy + C1F) * (2.0f * vxy + C2F);
            float den = (mxx + myy + C1F) * (vx + vy + C2F);
            ssum = fmaf(num, __builtin_amdgcn_rcpf(den), ssum);
        }
    }

    // ---- Block reduction (deterministic) ----
    #pragma unroll
    for (int off = 32; off > 0; off >>= 1)
        ssum += __shfl_down(ssum, off, 64);
    if ((tid & 63) == 0) red[tid >> 6] = ssum;
    __syncthreads();
    if (tid == 0) {
        float tot = red[0] + red[1] + red[2] + red[3];
        int bi = (blockIdx.z * gridDim.y + blockIdx.y) * gridDim.x + blockIdx.x;
        partial[bi] = tot;
    }
}

__global__ __launch_bounds__(1024)
void ssim_final(const float* __restrict__ partial, float* __restrict__ out) {
    __shared__ float red[16];
    float s = 0.0f;
    for (int i = threadIdx.x; i < NBLK; i += 1024) s += partial[i];
    #pragma unroll
    for (int off = 32; off > 0; off >>= 1)
        s += __shfl_down(s, off, 64);
    if ((threadIdx.x & 63) == 0) red[threadIdx.x >> 6] = s;
    __syncthreads();
    if (threadIdx.x == 0) {
        float tot = 0.0f;
        #pragma unroll
        for (int i = 0; i < 16; ++i) tot += red[i];
        out[0] = 1.0f - tot * (1.0f / 16777216.0f);
    }
}

extern "C" void kernel_launch(void* const* d_in, const int* in_sizes, int n_in,
                              void* d_out, int out_size, void* d_ws, size_t ws_size,
                              hipStream_t stream) {
    const float* x = (const float*)d_in[0];
    const float* y = (const float*)d_in[1];
    float* out     = (float*)d_out;
    float* partial = (float*)d_ws;   // NBLK floats = 32 KB

    dim3 grid(IMG / TS_C, IMG / TS_R, NIMG);   // (8, 16, 64)
    ssim_main<<<grid, 256, 0, stream>>>(x, y, partial);
    ssim_final<<<1, 1024, 0, stream>>>(partial, out);
}